// Round 1
// baseline (1211.203 us; speedup 1.0000x reference)
//
#include <hip/hip_runtime.h>
#include <hip/hip_bf16.h>

#define N_NODES 50000
#define N_EDGES 800000
#define D 128
#define NLAYERS 3
#define N_CLASSES 10
#define NUM_GRAPHS 256
#define BN_EPS 1e-5f

typedef __attribute__((ext_vector_type(2))) float f2;
typedef __attribute__((ext_vector_type(4))) float f4;

// ---------------- setup kernels ----------------

__global__ void k_init(int* __restrict__ deg, int* __restrict__ fill,
                       float* __restrict__ stats, int* __restrict__ gp) {
    int i = blockIdx.x * blockDim.x + threadIdx.x;
    if (i < N_NODES) { deg[i] = 0; fill[i] = 0; }
    if (i < 2 * D) stats[i] = 0.f;
    if (i <= NUM_GRAPHS) gp[i] = N_NODES;
}

__global__ void k_hist(const int* __restrict__ dst, int* __restrict__ deg) {
    int e = blockIdx.x * blockDim.x + threadIdx.x;
    if (e < N_EDGES) atomicAdd(&deg[dst[e]], 1);
}

__global__ void k_scan(const int* __restrict__ deg, int* __restrict__ row_ptr) {
    __shared__ int sm[1024];
    __shared__ int base_s;
    int tid = threadIdx.x;
    if (tid == 0) base_s = 0;
    __syncthreads();
    for (int start = 0; start < N_NODES; start += 1024) {
        int i = start + tid;
        int v = (i < N_NODES) ? deg[i] : 0;
        sm[tid] = v;
        __syncthreads();
        for (int off = 1; off < 1024; off <<= 1) {
            int t = (tid >= off) ? sm[tid - off] : 0;
            __syncthreads();
            sm[tid] += t;
            __syncthreads();
        }
        int incl = sm[tid];
        int base = base_s;
        if (i < N_NODES) row_ptr[i] = base + incl - v;
        __syncthreads();
        if (tid == 1023) base_s = base + incl;
        __syncthreads();
    }
    if (tid == 0) row_ptr[N_NODES] = base_s;
}

__global__ void k_scatter(const int* __restrict__ src, const int* __restrict__ dst,
                          const int* __restrict__ row_ptr, int* __restrict__ fill,
                          int* __restrict__ csr) {
    int e = blockIdx.x * blockDim.x + threadIdx.x;
    if (e < N_EDGES) {
        int d = dst[e];
        int p = atomicAdd(&fill[d], 1);
        csr[row_ptr[d] + p] = src[e];
    }
}

__global__ void k_bounds(const int* __restrict__ batch, int* __restrict__ gp) {
    int n = blockIdx.x * blockDim.x + threadIdx.x;
    if (n < N_NODES) atomicMin(&gp[batch[n]], n);
}

__global__ void k_fix(int* __restrict__ gp) {
    if (threadIdx.x == 0) {
        int m = N_NODES;
        for (int g = NUM_GRAPHS; g >= 0; g--) {
            if (gp[g] > m) gp[g] = m; else m = gp[g];
        }
    }
}

// ---------------- aggregation: u = t(h[n]) + sum t(h[src]) ----------------
// t = identity (layer 0) or relu(a*x + c) (fused BN+ReLU of previous layer)

template <bool APPLY_T>
__global__ __launch_bounds__(256) void k_agg(const float* __restrict__ H,
                                             const float* __restrict__ ac,
                                             const int* __restrict__ row_ptr,
                                             const int* __restrict__ csr,
                                             float* __restrict__ U) {
    int wave = (blockIdx.x * blockDim.x + threadIdx.x) >> 6;
    int lane = threadIdx.x & 63;
    if (wave >= N_NODES) return;
    int f = lane * 2;
    float a0 = 0.f, c0 = 0.f, a1 = 0.f, c1 = 0.f;
    if (APPLY_T) { a0 = ac[f]; c0 = ac[D + f]; a1 = ac[f + 1]; c1 = ac[D + f + 1]; }
    f2 self = *(const f2*)&H[(size_t)wave * D + f];
    float s0, s1;
    if (APPLY_T) { s0 = fmaxf(self.x * a0 + c0, 0.f); s1 = fmaxf(self.y * a1 + c1, 0.f); }
    else         { s0 = self.x; s1 = self.y; }
    int beg = row_ptr[wave], end = row_ptr[wave + 1];
    for (int j = beg; j < end; j++) {
        int s = csr[j];
        f2 v = *(const f2*)&H[(size_t)s * D + f];
        if (APPLY_T) { s0 += fmaxf(v.x * a0 + c0, 0.f); s1 += fmaxf(v.y * a1 + c1, 0.f); }
        else         { s0 += v.x; s1 += v.y; }
    }
    f2 o; o.x = s0; o.y = s1;
    *(f2*)&U[(size_t)wave * D + f] = o;
}

// ---------------- GEMM: Z = t(A) @ W + bias ----------------
// t = identity or relu(a*x+c) applied to the input (fused BN+ReLU)

template <bool APPLY_IN>
__global__ __launch_bounds__(256) void k_gemm(const float* __restrict__ A,
                                              const float* __restrict__ W,
                                              const float* __restrict__ bias,
                                              const float* __restrict__ ac,
                                              float* __restrict__ Z, int M) {
    __shared__ float a_sm[32][68];   // [k][row], transposed A tile
    __shared__ float b_sm[32][132];  // [k][col]
    __shared__ float ac_sm[2 * D];
    int tid = threadIdx.x;
    if (APPLY_IN) ac_sm[tid] = ac[tid];  // 256 threads, 256 elems
    int row0 = blockIdx.x * 64;
    int tx = tid & 15, ty = tid >> 4;
    float acc[4][8];
    {
        float bv[8];
#pragma unroll
        for (int c = 0; c < 8; c++) bv[c] = bias[tx * 8 + c];
#pragma unroll
        for (int r = 0; r < 4; r++)
#pragma unroll
            for (int c = 0; c < 8; c++) acc[r][c] = bv[c];
    }
    int lrow = tid >> 2;        // 0..63
    int lk   = (tid & 3) * 8;   // 0,8,16,24
    int bk   = tid >> 3;        // 0..31
    int bcol = (tid & 7) * 16;  // 0..112
    bool rowok = (row0 + lrow) < M;

    for (int kk = 0; kk < D; kk += 32) {
        __syncthreads();
        f4 av0, av1;
        if (rowok) {
            av0 = *(const f4*)&A[(size_t)(row0 + lrow) * D + kk + lk];
            av1 = *(const f4*)&A[(size_t)(row0 + lrow) * D + kk + lk + 4];
        } else { av0 = 0.f; av1 = 0.f; }
        float va[8] = {av0.x, av0.y, av0.z, av0.w, av1.x, av1.y, av1.z, av1.w};
#pragma unroll
        for (int i = 0; i < 8; i++) {
            float v = va[i];
            if (APPLY_IN) {
                int kidx = kk + lk + i;
                v = fmaxf(v * ac_sm[kidx] + ac_sm[D + kidx], 0.f);
            }
            a_sm[lk + i][lrow] = v;
        }
#pragma unroll
        for (int i = 0; i < 4; i++) {
            f4 wv = *(const f4*)&W[(size_t)(kk + bk) * D + bcol + i * 4];
            *(f4*)&b_sm[bk][bcol + i * 4] = wv;
        }
        __syncthreads();
#pragma unroll
        for (int k = 0; k < 32; k++) {
            f4 a4  = *(const f4*)&a_sm[k][ty * 4];
            f4 b40 = *(const f4*)&b_sm[k][tx * 8];
            f4 b41 = *(const f4*)&b_sm[k][tx * 8 + 4];
            float ar[4] = {a4.x, a4.y, a4.z, a4.w};
            float br[8] = {b40.x, b40.y, b40.z, b40.w, b41.x, b41.y, b41.z, b41.w};
#pragma unroll
            for (int r = 0; r < 4; r++)
#pragma unroll
                for (int c = 0; c < 8; c++) acc[r][c] += ar[r] * br[c];
        }
    }
#pragma unroll
    for (int r = 0; r < 4; r++) {
        int row = row0 + ty * 4 + r;
        if (row < M) {
            f4 o0, o1;
            o0.x = acc[r][0]; o0.y = acc[r][1]; o0.z = acc[r][2]; o0.w = acc[r][3];
            o1.x = acc[r][4]; o1.y = acc[r][5]; o1.z = acc[r][6]; o1.w = acc[r][7];
            *(f4*)&Z[(size_t)row * D + tx * 8]     = o0;
            *(f4*)&Z[(size_t)row * D + tx * 8 + 4] = o1;
        }
    }
}

// ---------------- BN stats / coef ----------------

__global__ void k_stats(const float* __restrict__ Z, float* __restrict__ stats, int M) {
    int col = threadIdx.x;  // 128
    float s = 0.f, q = 0.f;
    for (int r = blockIdx.x; r < M; r += gridDim.x) {
        float v = Z[(size_t)r * D + col];
        s += v; q += v * v;
    }
    atomicAdd(&stats[col], s);
    atomicAdd(&stats[D + col], q);
}

__global__ void k_coef(float* __restrict__ stats, const float* __restrict__ g,
                       const float* __restrict__ bt, float* __restrict__ ac) {
    int t = threadIdx.x;  // 128
    float mu = stats[t] * (1.0f / N_NODES);
    float var = stats[D + t] * (1.0f / N_NODES) - mu * mu;
    float inv = rsqrtf(var + BN_EPS);
    float a = g[t] * inv;
    float c = bt[t] - mu * a;
    ac[t] = a; ac[D + t] = c;
    stats[t] = 0.f; stats[D + t] = 0.f;  // ready for next BN
}

// ---------------- readout: per-graph sum of relu(a*z+c) ----------------

__global__ void k_readout(const float* __restrict__ Z, const float* __restrict__ ac,
                          const int* __restrict__ gp, float* __restrict__ ro, int layer) {
    int g = blockIdx.x;
    int col = threadIdx.x;  // 128
    float a = ac[col], c = ac[D + col];
    float s = 0.f;
    int beg = gp[g], end = gp[g + 1];
    for (int n = beg; n < end; n++) {
        float v = Z[(size_t)n * D + col] * a + c;
        s += fmaxf(v, 0.f);
    }
    ro[g * (NLAYERS * D) + layer * D + col] = s;
}

// ---------------- classifier ----------------

__global__ void k_cls(const float* __restrict__ ro, const float* __restrict__ Wc1,
                      const float* __restrict__ bc1, const float* __restrict__ Wc2,
                      const float* __restrict__ bc2, float* __restrict__ out) {
    __shared__ float r_sm[NLAYERS * D];
    __shared__ float h_sm[D];
    int g = blockIdx.x;
    int t = threadIdx.x;  // 128
    for (int i = t; i < NLAYERS * D; i += D) r_sm[i] = ro[g * (NLAYERS * D) + i];
    __syncthreads();
    float acc = bc1[t];
    for (int k = 0; k < NLAYERS * D; k++) acc += r_sm[k] * Wc1[(size_t)k * D + t];
    h_sm[t] = fmaxf(acc, 0.f);
    __syncthreads();
    if (t < N_CLASSES) {
        float o = bc2[t];
        for (int k = 0; k < D; k++) o += h_sm[k] * Wc2[k * N_CLASSES + t];
        out[g * N_CLASSES + t] = o;
    }
}

// ---------------- launch ----------------

extern "C" void kernel_launch(void* const* d_in, const int* in_sizes, int n_in,
                              void* d_out, int out_size, void* d_ws, size_t ws_size,
                              hipStream_t stream) {
    const float* x   = (const float*)d_in[0];
    const int*   ei  = (const int*)d_in[1];
    const int*   bat = (const int*)d_in[2];
    const float* W1  = (const float*)d_in[3];
    const float* b1  = (const float*)d_in[4];
    const float* g1  = (const float*)d_in[5];
    const float* bt1 = (const float*)d_in[6];
    const float* W2  = (const float*)d_in[7];
    const float* b2  = (const float*)d_in[8];
    const float* g2  = (const float*)d_in[9];
    const float* bt2 = (const float*)d_in[10];
    const float* Wc1 = (const float*)d_in[11];
    const float* bc1 = (const float*)d_in[12];
    const float* Wc2 = (const float*)d_in[13];
    const float* bc2 = (const float*)d_in[14];
    float* out = (float*)d_out;

    const int* src = ei;
    const int* dst = ei + N_EDGES;

    char* ws = (char*)d_ws;
    size_t off = 0;
    auto alloc = [&](size_t bytes) -> void* {
        void* p = ws + off;
        off += (bytes + 255) & ~(size_t)255;
        return p;
    };
    const size_t NB = (size_t)N_NODES * D * sizeof(float);
    float* bufA   = (float*)alloc(NB);
    float* bufB   = (float*)alloc(NB);
    float* bufC   = (float*)alloc(NB);
    int*   deg    = (int*)alloc(N_NODES * sizeof(int));
    int*   fill   = (int*)alloc(N_NODES * sizeof(int));
    int*   rowp   = (int*)alloc((N_NODES + 1) * sizeof(int));
    int*   csr    = (int*)alloc(N_EDGES * sizeof(int));
    int*   gp     = (int*)alloc((NUM_GRAPHS + 1) * sizeof(int));
    float* stats  = (float*)alloc(2 * D * sizeof(float));
    float* ac1    = (float*)alloc(2 * D * sizeof(float));
    float* ac2    = (float*)alloc(2 * D * sizeof(float));
    float* ro     = (float*)alloc((size_t)NUM_GRAPHS * NLAYERS * D * sizeof(float));

    k_init<<<(N_NODES + 255) / 256, 256, 0, stream>>>(deg, fill, stats, gp);
    k_hist<<<(N_EDGES + 255) / 256, 256, 0, stream>>>(dst, deg);
    k_scan<<<1, 1024, 0, stream>>>(deg, rowp);
    k_scatter<<<(N_EDGES + 255) / 256, 256, 0, stream>>>(src, dst, rowp, fill, csr);
    k_bounds<<<(N_NODES + 255) / 256, 256, 0, stream>>>(bat, gp);
    k_fix<<<1, 64, 0, stream>>>(gp);

    const int gemm_grid = (N_NODES + 63) / 64;
    const float* H = x;
    for (int i = 0; i < NLAYERS; i++) {
        if (i == 0)
            k_agg<false><<<(N_NODES + 3) / 4, 256, 0, stream>>>(H, nullptr, rowp, csr, bufA);
        else
            k_agg<true><<<(N_NODES + 3) / 4, 256, 0, stream>>>(H, ac2, rowp, csr, bufA);
        k_gemm<false><<<gemm_grid, 256, 0, stream>>>(bufA, W1 + (size_t)i * D * D,
                                                     b1 + i * D, nullptr, bufB, N_NODES);
        k_stats<<<256, 128, 0, stream>>>(bufB, stats, N_NODES);
        k_coef<<<1, 128, 0, stream>>>(stats, g1 + i * D, bt1 + i * D, ac1);
        k_gemm<true><<<gemm_grid, 256, 0, stream>>>(bufB, W2 + (size_t)i * D * D,
                                                    b2 + i * D, ac1, bufC, N_NODES);
        k_stats<<<256, 128, 0, stream>>>(bufC, stats, N_NODES);
        k_coef<<<1, 128, 0, stream>>>(stats, g2 + i * D, bt2 + i * D, ac2);
        k_readout<<<NUM_GRAPHS, 128, 0, stream>>>(bufC, ac2, gp, ro, i);
        H = bufC;
    }
    k_cls<<<NUM_GRAPHS, 128, 0, stream>>>(ro, Wc1, bc1, Wc2, bc2, out);
}

// Round 2
// 715.812 us; speedup vs baseline: 1.6921x; 1.6921x over previous
//
#include <hip/hip_runtime.h>

#define N_NODES 50000
#define N_EDGES 800000
#define D 128
#define NLAYERS 3
#define N_CLASSES 10
#define NUM_GRAPHS 256
#define BN_EPS 1e-5f

typedef __attribute__((ext_vector_type(4))) float f4;
typedef __attribute__((ext_vector_type(2))) float f2;
typedef __attribute__((ext_vector_type(8))) short short8;
typedef __attribute__((ext_vector_type(4))) unsigned short us4;

__device__ inline float b2f(unsigned short u) {
    unsigned int i = ((unsigned int)u) << 16;
    return __builtin_bit_cast(float, i);
}
__device__ inline unsigned short f2b(float f) {
    unsigned int u = __builtin_bit_cast(unsigned int, f);
    unsigned int r = (u + 0x7FFFu + ((u >> 16) & 1u)) >> 16;  // RNE
    return (unsigned short)r;
}

// ---------------- setup kernels ----------------

__global__ void k_init(int* __restrict__ deg, int* __restrict__ fill,
                       float* __restrict__ stats, int* __restrict__ gp,
                       float* __restrict__ ro) {
    int i = blockIdx.x * blockDim.x + threadIdx.x;  // 50176 threads
    if (i < N_NODES) { deg[i] = 0; fill[i] = 0; }
    if (i < 2 * D) stats[i] = 0.f;
    if (i <= NUM_GRAPHS) gp[i] = N_NODES;
    for (int j = i; j < NUM_GRAPHS * NLAYERS * D; j += 50176) ro[j] = 0.f;
}

__global__ void k_hist(const int* __restrict__ dst, int* __restrict__ deg) {
    int e = blockIdx.x * blockDim.x + threadIdx.x;
    if (e < N_EDGES) atomicAdd(&deg[dst[e]], 1);
}

__global__ void k_scan(const int* __restrict__ deg, int* __restrict__ rowp) {
    __shared__ int sm[1024];
    int tid = threadIdx.x;
    const int PER = (N_NODES + 1023) / 1024;  // 49
    int base = tid * PER;
    int s = 0;
    for (int j = 0; j < PER; j++) {
        int i = base + j;
        if (i < N_NODES) s += deg[i];
    }
    sm[tid] = s;
    __syncthreads();
    for (int off = 1; off < 1024; off <<= 1) {
        int t = (tid >= off) ? sm[tid - off] : 0;
        __syncthreads();
        sm[tid] += t;
        __syncthreads();
    }
    int run = sm[tid] - s;  // exclusive
    for (int j = 0; j < PER; j++) {
        int i = base + j;
        if (i < N_NODES) { rowp[i] = run; run += deg[i]; }
    }
    if (tid == 1023) rowp[N_NODES] = run;
}

__global__ void k_scatter(const int* __restrict__ src, const int* __restrict__ dst,
                          const int* __restrict__ rowp, int* __restrict__ fill,
                          int* __restrict__ csr) {
    int e = blockIdx.x * blockDim.x + threadIdx.x;
    if (e < N_EDGES) {
        int d = dst[e];
        int p = atomicAdd(&fill[d], 1);
        csr[rowp[d] + p] = src[e];
    }
}

__global__ void k_bounds(const int* __restrict__ batch, int* __restrict__ gp) {
    int n = blockIdx.x * blockDim.x + threadIdx.x;
    if (n < N_NODES) atomicMin(&gp[batch[n]], n);
}

__global__ void k_fix(int* __restrict__ gp) {
    if (threadIdx.x == 0) {
        int m = N_NODES;
        for (int g = NUM_GRAPHS; g >= 0; g--) {
            if (gp[g] > m) gp[g] = m; else m = gp[g];
        }
    }
}

__global__ void k_xcast(const f4* __restrict__ x, us4* __restrict__ xb) {
    int i = blockIdx.x * blockDim.x + threadIdx.x;
    if (i < N_NODES * D / 4) {
        f4 v = x[i];
        us4 o;
        o[0] = f2b(v.x); o[1] = f2b(v.y); o[2] = f2b(v.z); o[3] = f2b(v.w);
        xb[i] = o;
    }
}

// Weights -> bf16 fragment order: Wb[m][f=ct*4+ks][lane][j] = W[m][ks*32+(l>>4)*8+j][ct*16+(l&15)]
__global__ void k_wprep(const float* __restrict__ W1, const float* __restrict__ W2,
                        short8* __restrict__ Wb) {
    int t = blockIdx.x * blockDim.x + threadIdx.x;
    if (t >= 6 * 32 * 64) return;
    int m = t >> 11;
    int f = (t >> 6) & 31;
    int l = t & 63;
    int ct = f >> 2, ks = f & 3;
    int n = ct * 16 + (l & 15);
    int k0 = ks * 32 + (l >> 4) * 8;
    const float* Wsrc = (m < 3) ? (W1 + (size_t)m * D * D) : (W2 + (size_t)(m - 3) * D * D);
    short8 o;
#pragma unroll
    for (int j = 0; j < 8; j++) o[j] = (short)f2b(Wsrc[(size_t)(k0 + j) * D + n]);
    Wb[t] = o;
}

// ---------------- aggregation (bf16 in/out, fp32 accum) ----------------
// u = t(h[n]) + sum_{j->n} t(h[j]),  t = identity or relu(a*x+c)

template <bool APPLY_T>
__global__ __launch_bounds__(256) void k_agg(const us4* __restrict__ H,
                                             const float* __restrict__ ac,
                                             const int* __restrict__ rowp,
                                             const int* __restrict__ csr,
                                             us4* __restrict__ U) {
    int gid = blockIdx.x * blockDim.x + threadIdx.x;
    int node = gid >> 5;
    int lane = threadIdx.x & 31;
    if (node >= N_NODES) return;
    f4 av, cv;
    if (APPLY_T) {
        av = *((const f4*)ac + lane);
        cv = *((const f4*)(ac + D) + lane);
    }
    us4 sv = H[(size_t)node * 32 + lane];
    f4 s;
    if (APPLY_T) {
        s.x = fmaxf(b2f(sv[0]) * av.x + cv.x, 0.f);
        s.y = fmaxf(b2f(sv[1]) * av.y + cv.y, 0.f);
        s.z = fmaxf(b2f(sv[2]) * av.z + cv.z, 0.f);
        s.w = fmaxf(b2f(sv[3]) * av.w + cv.w, 0.f);
    } else {
        s.x = b2f(sv[0]); s.y = b2f(sv[1]); s.z = b2f(sv[2]); s.w = b2f(sv[3]);
    }
    int beg = rowp[node], end = rowp[node + 1];
    for (int j = beg; j < end; j++) {
        int sn = csr[j];
        us4 v = H[(size_t)sn * 32 + lane];
        if (APPLY_T) {
            s.x += fmaxf(b2f(v[0]) * av.x + cv.x, 0.f);
            s.y += fmaxf(b2f(v[1]) * av.y + cv.y, 0.f);
            s.z += fmaxf(b2f(v[2]) * av.z + cv.z, 0.f);
            s.w += fmaxf(b2f(v[3]) * av.w + cv.w, 0.f);
        } else {
            s.x += b2f(v[0]); s.y += b2f(v[1]); s.z += b2f(v[2]); s.w += b2f(v[3]);
        }
    }
    us4 o;
    o[0] = f2b(s.x); o[1] = f2b(s.y); o[2] = f2b(s.z); o[3] = f2b(s.w);
    U[(size_t)node * 32 + lane] = o;
}

// ---------------- MFMA GEMM: Z = t(A) @ W + bias, fused column stats ----------------
// A bf16 [M][128]; Wb fragment-order bf16; Z bf16 out; stats += colsum/colsumsq (fp32)

template <bool TRANS>
__global__ __launch_bounds__(256) void k_gemm(const unsigned short* __restrict__ A,
                                              const short8* __restrict__ Wb,
                                              const float* __restrict__ bias,
                                              const float* __restrict__ ac,
                                              unsigned short* __restrict__ Z,
                                              float* __restrict__ stats, int M) {
    __shared__ float lds_s[D], lds_q[D];
    int tid = threadIdx.x;
    if (tid < D) { lds_s[tid] = 0.f; lds_q[tid] = 0.f; }
    int w = tid >> 6, l = tid & 63;
    int lr = l & 15, lg = l >> 4;
    int rowb = blockIdx.x * 64 + w * 16;
    int arow = rowb + lr;
    int arow_c = arow < M ? arow : M - 1;
    f4 acc[8];
#pragma unroll
    for (int ct = 0; ct < 8; ct++) {
        float bv = bias[ct * 16 + lr];
        acc[ct].x = bv; acc[ct].y = bv; acc[ct].z = bv; acc[ct].w = bv;
    }
    __syncthreads();  // LDS zero visible before epilogue atomics

#pragma unroll
    for (int ks = 0; ks < 4; ks++) {
        short8 a;
        if (!TRANS) {
            a = *(const short8*)(A + (size_t)arow_c * D + ks * 32 + lg * 8);
        } else {
            int k0 = ks * 32 + lg * 8;
            const unsigned short* ap = A + (size_t)arow_c * D + k0;
            us4 v0 = *(const us4*)ap;
            us4 v1 = *(const us4*)(ap + 4);
            f4 a0 = *(const f4*)(ac + k0);
            f4 a1 = *(const f4*)(ac + k0 + 4);
            f4 c0 = *(const f4*)(ac + D + k0);
            f4 c1 = *(const f4*)(ac + D + k0 + 4);
            a[0] = (short)f2b(fmaxf(b2f(v0[0]) * a0.x + c0.x, 0.f));
            a[1] = (short)f2b(fmaxf(b2f(v0[1]) * a0.y + c0.y, 0.f));
            a[2] = (short)f2b(fmaxf(b2f(v0[2]) * a0.z + c0.z, 0.f));
            a[3] = (short)f2b(fmaxf(b2f(v0[3]) * a0.w + c0.w, 0.f));
            a[4] = (short)f2b(fmaxf(b2f(v1[0]) * a1.x + c1.x, 0.f));
            a[5] = (short)f2b(fmaxf(b2f(v1[1]) * a1.y + c1.y, 0.f));
            a[6] = (short)f2b(fmaxf(b2f(v1[2]) * a1.z + c1.z, 0.f));
            a[7] = (short)f2b(fmaxf(b2f(v1[3]) * a1.w + c1.w, 0.f));
        }
#pragma unroll
        for (int ct = 0; ct < 8; ct++) {
            short8 b = Wb[(ct * 4 + ks) * 64 + l];
            acc[ct] = __builtin_amdgcn_mfma_f32_16x16x32_bf16(a, b, acc[ct], 0, 0, 0);
        }
    }

    float vm[4];
#pragma unroll
    for (int r = 0; r < 4; r++) vm[r] = (rowb + lg * 4 + r) < M ? 1.f : 0.f;
#pragma unroll
    for (int ct = 0; ct < 8; ct++) {
        float s = 0.f, q = 0.f;
#pragma unroll
        for (int r = 0; r < 4; r++) {
            float v = acc[ct][r];
            s += v * vm[r];
            q += v * v * vm[r];
            int rd = rowb + lg * 4 + r;
            if (rd < M) Z[(size_t)rd * D + ct * 16 + lr] = f2b(v);
        }
        s += __shfl_xor(s, 16);
        s += __shfl_xor(s, 32);
        q += __shfl_xor(q, 16);
        q += __shfl_xor(q, 32);
        if (lg == 0) {
            atomicAdd(&lds_s[ct * 16 + lr], s);
            atomicAdd(&lds_q[ct * 16 + lr], q);
        }
    }
    __syncthreads();
    if (tid < D) {
        atomicAdd(&stats[tid], lds_s[tid]);
        atomicAdd(&stats[D + tid], lds_q[tid]);
    }
}

// ---------------- BN coef ----------------

__global__ void k_coef(float* __restrict__ stats, const float* __restrict__ g,
                       const float* __restrict__ bt, float* __restrict__ ac) {
    int t = threadIdx.x;  // 128
    float mu = stats[t] * (1.0f / N_NODES);
    float var = stats[D + t] * (1.0f / N_NODES) - mu * mu;
    float inv = rsqrtf(var + BN_EPS);
    float a = g[t] * inv;
    float c = bt[t] - mu * a;
    ac[t] = a; ac[D + t] = c;
    stats[t] = 0.f; stats[D + t] = 0.f;
}

// ---------------- readout: per-graph sum of relu(a*z+c), chunked ----------------

__global__ __launch_bounds__(256) void k_readout(const unsigned int* __restrict__ Zb,
                                                 const float* __restrict__ ac,
                                                 const int* __restrict__ gp,
                                                 const int* __restrict__ batch,
                                                 float* __restrict__ ro, int layer) {
    __shared__ f2 sm[256];
    int tid = threadIdx.x;
    int n0 = blockIdx.x * 256;
    int n1 = n0 + 256; if (n1 > N_NODES) n1 = N_NODES;
    int g_lo = batch[n0], g_hi = batch[n1 - 1];
    int grp = tid >> 6, cw = tid & 63;
    float a0 = ac[2 * cw], a1 = ac[2 * cw + 1];
    float c0 = ac[D + 2 * cw], c1 = ac[D + 2 * cw + 1];
    for (int g = g_lo; g <= g_hi; g++) {
        int beg = gp[g]; if (beg < n0) beg = n0;
        int end = gp[g + 1]; if (end > n1) end = n1;
        f2 acc; acc.x = 0.f; acc.y = 0.f;
        for (int r = beg + grp; r < end; r += 4) {
            unsigned int v = Zb[(size_t)r * 64 + cw];
            float x0 = b2f((unsigned short)(v & 0xFFFFu));
            float x1 = b2f((unsigned short)(v >> 16));
            acc.x += fmaxf(x0 * a0 + c0, 0.f);
            acc.y += fmaxf(x1 * a1 + c1, 0.f);
        }
        sm[tid] = acc;
        __syncthreads();
        if (tid < 64) {
            f2 t = sm[tid];
            t.x += sm[tid + 64].x + sm[tid + 128].x + sm[tid + 192].x;
            t.y += sm[tid + 64].y + sm[tid + 128].y + sm[tid + 192].y;
            atomicAdd(&ro[(size_t)g * (NLAYERS * D) + layer * D + 2 * cw], t.x);
            atomicAdd(&ro[(size_t)g * (NLAYERS * D) + layer * D + 2 * cw + 1], t.y);
        }
        __syncthreads();
    }
}

// ---------------- classifier ----------------

__global__ void k_cls(const float* __restrict__ ro, const float* __restrict__ Wc1,
                      const float* __restrict__ bc1, const float* __restrict__ Wc2,
                      const float* __restrict__ bc2, float* __restrict__ out) {
    __shared__ float r_sm[NLAYERS * D];
    __shared__ float h_sm[D];
    int g = blockIdx.x;
    int t = threadIdx.x;  // 128
    for (int i = t; i < NLAYERS * D; i += D) r_sm[i] = ro[(size_t)g * (NLAYERS * D) + i];
    __syncthreads();
    float acc = bc1[t];
    for (int k = 0; k < NLAYERS * D; k++) acc += r_sm[k] * Wc1[(size_t)k * D + t];
    h_sm[t] = fmaxf(acc, 0.f);
    __syncthreads();
    if (t < N_CLASSES) {
        float o = bc2[t];
        for (int k = 0; k < D; k++) o += h_sm[k] * Wc2[k * N_CLASSES + t];
        out[g * N_CLASSES + t] = o;
    }
}

// ---------------- launch ----------------

extern "C" void kernel_launch(void* const* d_in, const int* in_sizes, int n_in,
                              void* d_out, int out_size, void* d_ws, size_t ws_size,
                              hipStream_t stream) {
    const float* x   = (const float*)d_in[0];
    const int*   ei  = (const int*)d_in[1];
    const int*   bat = (const int*)d_in[2];
    const float* W1  = (const float*)d_in[3];
    const float* b1  = (const float*)d_in[4];
    const float* g1  = (const float*)d_in[5];
    const float* bt1 = (const float*)d_in[6];
    const float* W2  = (const float*)d_in[7];
    const float* b2  = (const float*)d_in[8];
    const float* g2  = (const float*)d_in[9];
    const float* bt2 = (const float*)d_in[10];
    const float* Wc1 = (const float*)d_in[11];
    const float* bc1 = (const float*)d_in[12];
    const float* Wc2 = (const float*)d_in[13];
    const float* bc2 = (const float*)d_in[14];
    float* out = (float*)d_out;

    const int* src = ei;
    const int* dst = ei + N_EDGES;

    char* ws = (char*)d_ws;
    size_t off = 0;
    auto alloc = [&](size_t bytes) -> void* {
        void* p = ws + off;
        off += (bytes + 255) & ~(size_t)255;
        return p;
    };
    const size_t NBH = (size_t)N_NODES * D * sizeof(unsigned short);  // bf16 node buf
    unsigned short* xb   = (unsigned short*)alloc(NBH);
    unsigned short* bufA = (unsigned short*)alloc(NBH);
    unsigned short* bufB = (unsigned short*)alloc(NBH);
    unsigned short* bufC = (unsigned short*)alloc(NBH);
    short8* Wb   = (short8*)alloc(6 * 32 * 64 * sizeof(short8));
    int*   deg   = (int*)alloc(N_NODES * sizeof(int));
    int*   fill  = (int*)alloc(N_NODES * sizeof(int));
    int*   rowp  = (int*)alloc((N_NODES + 1) * sizeof(int));
    int*   csr   = (int*)alloc(N_EDGES * sizeof(int));
    int*   gp    = (int*)alloc((NUM_GRAPHS + 1) * sizeof(int));
    float* stats = (float*)alloc(2 * D * sizeof(float));
    float* ac1   = (float*)alloc(2 * D * sizeof(float));
    float* ac2   = (float*)alloc(2 * D * sizeof(float));
    float* ro    = (float*)alloc((size_t)NUM_GRAPHS * NLAYERS * D * sizeof(float));

    k_init<<<196, 256, 0, stream>>>(deg, fill, stats, gp, ro);
    k_hist<<<(N_EDGES + 255) / 256, 256, 0, stream>>>(dst, deg);
    k_scan<<<1, 1024, 0, stream>>>(deg, rowp);
    k_scatter<<<(N_EDGES + 255) / 256, 256, 0, stream>>>(src, dst, rowp, fill, csr);
    k_bounds<<<(N_NODES + 255) / 256, 256, 0, stream>>>(bat, gp);
    k_fix<<<1, 64, 0, stream>>>(gp);
    k_xcast<<<(N_NODES * D / 4 + 255) / 256, 256, 0, stream>>>((const f4*)x, (us4*)xb);
    k_wprep<<<48, 256, 0, stream>>>(W1, W2, Wb);

    const int agg_grid  = (N_NODES * 32 + 255) / 256;
    const int gemm_grid = (N_NODES + 63) / 64;
    const unsigned short* H = xb;
    for (int i = 0; i < NLAYERS; i++) {
        if (i == 0)
            k_agg<false><<<agg_grid, 256, 0, stream>>>((const us4*)H, nullptr, rowp, csr, (us4*)bufA);
        else
            k_agg<true><<<agg_grid, 256, 0, stream>>>((const us4*)H, ac2, rowp, csr, (us4*)bufA);
        k_gemm<false><<<gemm_grid, 256, 0, stream>>>(bufA, Wb + (size_t)i * 2048, b1 + i * D,
                                                     nullptr, bufB, stats, N_NODES);
        k_coef<<<1, 128, 0, stream>>>(stats, g1 + i * D, bt1 + i * D, ac1);
        k_gemm<true><<<gemm_grid, 256, 0, stream>>>(bufB, Wb + (size_t)(3 + i) * 2048, b2 + i * D,
                                                    ac1, bufC, stats, N_NODES);
        k_coef<<<1, 128, 0, stream>>>(stats, g2 + i * D, bt2 + i * D, ac2);
        k_readout<<<196, 256, 0, stream>>>((const unsigned int*)bufC, ac2, gp, bat, ro, i);
        H = bufC;
    }
    k_cls<<<NUM_GRAPHS, 128, 0, stream>>>(ro, Wc1, bc1, Wc2, bc2, out);
}

// Round 3
// 515.600 us; speedup vs baseline: 2.3491x; 1.3883x over previous
//
#include <hip/hip_runtime.h>

#define N_NODES 50000
#define N_EDGES 800000
#define D 128
#define NLAYERS 3
#define N_CLASSES 10
#define NUM_GRAPHS 256
#define BN_EPS 1e-5f

typedef __attribute__((ext_vector_type(4))) float f4;
typedef __attribute__((ext_vector_type(2))) float f2;
typedef __attribute__((ext_vector_type(8))) short short8;
typedef __attribute__((ext_vector_type(4))) unsigned short us4;

__device__ inline float b2f(unsigned short u) {
    unsigned int i = ((unsigned int)u) << 16;
    return __builtin_bit_cast(float, i);
}
__device__ inline unsigned short f2b(float f) {
    unsigned int u = __builtin_bit_cast(unsigned int, f);
    unsigned int r = (u + 0x7FFFu + ((u >> 16) & 1u)) >> 16;  // RNE
    return (unsigned short)r;
}

// BN coef into LDS: ac[0..127]=a, ac[128..255]=c  (z_norm = a*z + c)
__device__ inline void coef_to_lds(const float* __restrict__ stats,
                                   const float* __restrict__ g,
                                   const float* __restrict__ bt,
                                   float* ac_sm, int tid) {
    if (tid < D) {
        float mu = stats[tid] * (1.0f / N_NODES);
        float var = stats[D + tid] * (1.0f / N_NODES) - mu * mu;
        float inv = rsqrtf(var + BN_EPS);
        float a = g[tid] * inv;
        ac_sm[tid] = a;
        ac_sm[D + tid] = bt[tid] - mu * a;
    }
}

// ---------------- fused setup: hist + bounds + xcast + wprep ----------------
// grid: 3125 x 256 = 800000 threads exactly

__global__ __launch_bounds__(256) void k_pre(const int* __restrict__ dst,
                                             const int* __restrict__ bat,
                                             const float* __restrict__ x,
                                             const float* __restrict__ W1,
                                             const float* __restrict__ W2,
                                             int* __restrict__ deg,
                                             int* __restrict__ gp,
                                             us4* __restrict__ xb,
                                             short8* __restrict__ Wb) {
    int gid = blockIdx.x * 256 + threadIdx.x;
    atomicAdd(&deg[dst[gid]], 1);
    if (gid < N_NODES) atomicMin(&gp[bat[gid]], gid);
    const f4* xf = (const f4*)x;
#pragma unroll
    for (int rep = 0; rep < 2; rep++) {
        int i = gid + rep * 800000;  // 2*800000 == N_NODES*D/4
        f4 v = xf[i];
        us4 o;
        o[0] = f2b(v.x); o[1] = f2b(v.y); o[2] = f2b(v.z); o[3] = f2b(v.w);
        xb[i] = o;
    }
    if (gid < 6 * 32 * 64) {
        int m = gid >> 11;
        int f = (gid >> 6) & 31;
        int l = gid & 63;
        int ct = f >> 2, ks = f & 3;
        int n = ct * 16 + (l & 15);
        int k0 = ks * 32 + (l >> 4) * 8;
        const float* Wsrc = (m < 3) ? (W1 + (size_t)m * D * D) : (W2 + (size_t)(m - 3) * D * D);
        short8 o;
#pragma unroll
        for (int j = 0; j < 8; j++) o[j] = (short)f2b(Wsrc[(size_t)(k0 + j) * D + n]);
        Wb[gid] = o;
    }
}

// ---------------- hierarchical scan ----------------

__global__ void k_s1(const int* __restrict__ deg, int* __restrict__ bsum) {
    __shared__ int sm[256];
    int t = threadIdx.x;
    int i = blockIdx.x * 256 + t;
    int v = (i < N_NODES) ? deg[i] : 0;
    sm[t] = v;
    __syncthreads();
    for (int off = 128; off > 0; off >>= 1) {
        if (t < off) sm[t] += sm[t + off];
        __syncthreads();
    }
    if (t == 0) bsum[blockIdx.x] = sm[0];
}

// scan 196 partials (in-place -> exclusive) + rowp[N] + suffix-min fix of gp
__global__ void k_s2(int* __restrict__ bsum, int* __restrict__ gp, int* __restrict__ rowp) {
    __shared__ int sm[256];
    __shared__ int gm[257];
    int t = threadIdx.x;  // 256
    int v = (t < 196) ? bsum[t] : 0;
    sm[t] = v;
    gm[t] = min(gp[t], N_NODES);
    if (t == 0) gm[256] = N_NODES;
    __syncthreads();
    for (int off = 1; off < 256; off <<= 1) {
        int u = (t >= off) ? sm[t - off] : 0;
        __syncthreads();
        sm[t] += u;
        __syncthreads();
    }
    if (t < 196) bsum[t] = sm[t] - v;
    if (t == 195) rowp[N_NODES] = sm[t];
    for (int off = 1; off <= 256; off <<= 1) {
        int u = (t + off <= 256) ? gm[t + off] : N_NODES;
        __syncthreads();
        gm[t] = min(gm[t], u);
        __syncthreads();
    }
    gp[t] = gm[t];
    if (t == 0) gp[256] = N_NODES;
}

__global__ void k_s3(const int* __restrict__ deg, const int* __restrict__ bsum,
                     int* __restrict__ rowp) {
    __shared__ int sm[256];
    int t = threadIdx.x;
    int i = blockIdx.x * 256 + t;
    int v = (i < N_NODES) ? deg[i] : 0;
    sm[t] = v;
    __syncthreads();
    for (int off = 1; off < 256; off <<= 1) {
        int u = (t >= off) ? sm[t - off] : 0;
        __syncthreads();
        sm[t] += u;
        __syncthreads();
    }
    if (i < N_NODES) rowp[i] = bsum[blockIdx.x] + sm[t] - v;
}

__global__ void k_scatter(const int* __restrict__ src, const int* __restrict__ dst,
                          const int* __restrict__ rowp, int* __restrict__ fill,
                          int* __restrict__ csr) {
    int e = blockIdx.x * blockDim.x + threadIdx.x;
    if (e < N_EDGES) {
        int d = dst[e];
        int p = atomicAdd(&fill[d], 1);
        csr[rowp[d] + p] = src[e];
    }
}

// ---------------- aggregation (bf16 in/out, fp32 accum, inline BN coef) ----------------

template <bool APPLY_T>
__global__ __launch_bounds__(256) void k_agg(const us4* __restrict__ H,
                                             const float* __restrict__ stats,
                                             const float* __restrict__ g,
                                             const float* __restrict__ bt,
                                             const int* __restrict__ rowp,
                                             const int* __restrict__ csr,
                                             us4* __restrict__ U) {
    __shared__ float ac_sm[2 * D];
    int tid = threadIdx.x;
    if (APPLY_T) {
        coef_to_lds(stats, g, bt, ac_sm, tid);
        __syncthreads();
    }
    int gid = blockIdx.x * 256 + tid;
    int node = gid >> 5;
    int lane = tid & 31;
    if (node >= N_NODES) return;
    f4 av, cv;
    if (APPLY_T) {
        av = *(const f4*)&ac_sm[lane * 4];
        cv = *(const f4*)&ac_sm[D + lane * 4];
    }
    f4 s = {0.f, 0.f, 0.f, 0.f};
    auto accum = [&](us4 v) {
        if (APPLY_T) {
            s.x += fmaxf(b2f(v[0]) * av.x + cv.x, 0.f);
            s.y += fmaxf(b2f(v[1]) * av.y + cv.y, 0.f);
            s.z += fmaxf(b2f(v[2]) * av.z + cv.z, 0.f);
            s.w += fmaxf(b2f(v[3]) * av.w + cv.w, 0.f);
        } else {
            s.x += b2f(v[0]); s.y += b2f(v[1]); s.z += b2f(v[2]); s.w += b2f(v[3]);
        }
    };
    accum(H[(size_t)node * 32 + lane]);  // self
    int beg = rowp[node], end = rowp[node + 1];
    int j = beg;
    for (; j + 3 < end; j += 4) {
        int i0 = csr[j], i1 = csr[j + 1], i2 = csr[j + 2], i3 = csr[j + 3];
        us4 v0 = H[(size_t)i0 * 32 + lane];
        us4 v1 = H[(size_t)i1 * 32 + lane];
        us4 v2 = H[(size_t)i2 * 32 + lane];
        us4 v3 = H[(size_t)i3 * 32 + lane];
        accum(v0); accum(v1); accum(v2); accum(v3);
    }
    for (; j < end; j++) {
        int i0 = csr[j];
        accum(H[(size_t)i0 * 32 + lane]);
    }
    us4 o;
    o[0] = f2b(s.x); o[1] = f2b(s.y); o[2] = f2b(s.z); o[3] = f2b(s.w);
    U[(size_t)node * 32 + lane] = o;
}

// ---------------- MFMA GEMM: Z = t(A) @ W + bias, fused column stats ----------------

template <bool TRANS>
__global__ __launch_bounds__(256) void k_gemm(const unsigned short* __restrict__ A,
                                              const short8* __restrict__ Wb,
                                              const float* __restrict__ bias,
                                              const float* __restrict__ stats_in,
                                              const float* __restrict__ g,
                                              const float* __restrict__ bt,
                                              unsigned short* __restrict__ Z,
                                              float* __restrict__ stats_out, int M) {
    __shared__ float lds_s[D], lds_q[D];
    __shared__ float ac_sm[2 * D];
    int tid = threadIdx.x;
    if (tid < D) { lds_s[tid] = 0.f; lds_q[tid] = 0.f; }
    if (TRANS) coef_to_lds(stats_in, g, bt, ac_sm, tid);
    int w = tid >> 6, l = tid & 63;
    int lr = l & 15, lg = l >> 4;
    int rowb = blockIdx.x * 64 + w * 16;
    int arow = rowb + lr;
    int arow_c = arow < M ? arow : M - 1;
    f4 acc[8];
#pragma unroll
    for (int ct = 0; ct < 8; ct++) {
        float bv = bias[ct * 16 + lr];
        acc[ct].x = bv; acc[ct].y = bv; acc[ct].z = bv; acc[ct].w = bv;
    }
    __syncthreads();

#pragma unroll
    for (int ks = 0; ks < 4; ks++) {
        short8 a;
        if (!TRANS) {
            a = *(const short8*)(A + (size_t)arow_c * D + ks * 32 + lg * 8);
        } else {
            int k0 = ks * 32 + lg * 8;
            const unsigned short* ap = A + (size_t)arow_c * D + k0;
            us4 v0 = *(const us4*)ap;
            us4 v1 = *(const us4*)(ap + 4);
            f4 a0 = *(const f4*)&ac_sm[k0];
            f4 a1 = *(const f4*)&ac_sm[k0 + 4];
            f4 c0 = *(const f4*)&ac_sm[D + k0];
            f4 c1 = *(const f4*)&ac_sm[D + k0 + 4];
            a[0] = (short)f2b(fmaxf(b2f(v0[0]) * a0.x + c0.x, 0.f));
            a[1] = (short)f2b(fmaxf(b2f(v0[1]) * a0.y + c0.y, 0.f));
            a[2] = (short)f2b(fmaxf(b2f(v0[2]) * a0.z + c0.z, 0.f));
            a[3] = (short)f2b(fmaxf(b2f(v0[3]) * a0.w + c0.w, 0.f));
            a[4] = (short)f2b(fmaxf(b2f(v1[0]) * a1.x + c1.x, 0.f));
            a[5] = (short)f2b(fmaxf(b2f(v1[1]) * a1.y + c1.y, 0.f));
            a[6] = (short)f2b(fmaxf(b2f(v1[2]) * a1.z + c1.z, 0.f));
            a[7] = (short)f2b(fmaxf(b2f(v1[3]) * a1.w + c1.w, 0.f));
        }
#pragma unroll
        for (int ct = 0; ct < 8; ct++) {
            short8 b = Wb[(ct * 4 + ks) * 64 + l];
            acc[ct] = __builtin_amdgcn_mfma_f32_16x16x32_bf16(a, b, acc[ct], 0, 0, 0);
        }
    }

    float vm[4];
#pragma unroll
    for (int r = 0; r < 4; r++) vm[r] = (rowb + lg * 4 + r) < M ? 1.f : 0.f;
#pragma unroll
    for (int ct = 0; ct < 8; ct++) {
        float s = 0.f, q = 0.f;
#pragma unroll
        for (int r = 0; r < 4; r++) {
            float v = acc[ct][r];
            s += v * vm[r];
            q += v * v * vm[r];
            int rd = rowb + lg * 4 + r;
            if (rd < M) Z[(size_t)rd * D + ct * 16 + lr] = f2b(v);
        }
        s += __shfl_xor(s, 16);
        s += __shfl_xor(s, 32);
        q += __shfl_xor(q, 16);
        q += __shfl_xor(q, 32);
        if (lg == 0) {
            atomicAdd(&lds_s[ct * 16 + lr], s);
            atomicAdd(&lds_q[ct * 16 + lr], q);
        }
    }
    __syncthreads();
    if (tid < D) {
        atomicAdd(&stats_out[tid], lds_s[tid]);
        atomicAdd(&stats_out[D + tid], lds_q[tid]);
    }
}

// ---------------- readout: per-graph sum of relu(a*z+c), chunked, inline coef ----------------

__global__ __launch_bounds__(256) void k_readout(const unsigned int* __restrict__ Zb,
                                                 const float* __restrict__ stats,
                                                 const float* __restrict__ g,
                                                 const float* __restrict__ bt,
                                                 const int* __restrict__ gp,
                                                 const int* __restrict__ batch,
                                                 float* __restrict__ ro, int layer) {
    __shared__ f2 sm[256];
    __shared__ float ac_sm[2 * D];
    int tid = threadIdx.x;
    coef_to_lds(stats, g, bt, ac_sm, tid);
    __syncthreads();
    int n0 = blockIdx.x * 256;
    int n1 = n0 + 256; if (n1 > N_NODES) n1 = N_NODES;
    int g_lo = batch[n0], g_hi = batch[n1 - 1];
    int grp = tid >> 6, cw = tid & 63;
    float a0 = ac_sm[2 * cw], a1 = ac_sm[2 * cw + 1];
    float c0 = ac_sm[D + 2 * cw], c1 = ac_sm[D + 2 * cw + 1];
    for (int gg = g_lo; gg <= g_hi; gg++) {
        int beg = gp[gg]; if (beg < n0) beg = n0;
        int end = gp[gg + 1]; if (end > n1) end = n1;
        f2 acc; acc.x = 0.f; acc.y = 0.f;
        for (int r = beg + grp; r < end; r += 4) {
            unsigned int v = Zb[(size_t)r * 64 + cw];
            float x0 = b2f((unsigned short)(v & 0xFFFFu));
            float x1 = b2f((unsigned short)(v >> 16));
            acc.x += fmaxf(x0 * a0 + c0, 0.f);
            acc.y += fmaxf(x1 * a1 + c1, 0.f);
        }
        sm[tid] = acc;
        __syncthreads();
        if (tid < 64) {
            f2 t = sm[tid];
            t.x += sm[tid + 64].x + sm[tid + 128].x + sm[tid + 192].x;
            t.y += sm[tid + 64].y + sm[tid + 128].y + sm[tid + 192].y;
            atomicAdd(&ro[(size_t)gg * (NLAYERS * D) + layer * D + 2 * cw], t.x);
            atomicAdd(&ro[(size_t)gg * (NLAYERS * D) + layer * D + 2 * cw + 1], t.y);
        }
        __syncthreads();
    }
}

// ---------------- classifier ----------------

__global__ void k_cls(const float* __restrict__ ro, const float* __restrict__ Wc1,
                      const float* __restrict__ bc1, const float* __restrict__ Wc2,
                      const float* __restrict__ bc2, float* __restrict__ out) {
    __shared__ float r_sm[NLAYERS * D];
    __shared__ float h_sm[D];
    int g = blockIdx.x;
    int t = threadIdx.x;  // 128
    for (int i = t; i < NLAYERS * D; i += D) r_sm[i] = ro[(size_t)g * (NLAYERS * D) + i];
    __syncthreads();
    float acc = bc1[t];
    for (int k = 0; k < NLAYERS * D; k++) acc += r_sm[k] * Wc1[(size_t)k * D + t];
    h_sm[t] = fmaxf(acc, 0.f);
    __syncthreads();
    if (t < N_CLASSES) {
        float o = bc2[t];
        for (int k = 0; k < D; k++) o += h_sm[k] * Wc2[k * N_CLASSES + t];
        out[g * N_CLASSES + t] = o;
    }
}

// ---------------- launch ----------------

extern "C" void kernel_launch(void* const* d_in, const int* in_sizes, int n_in,
                              void* d_out, int out_size, void* d_ws, size_t ws_size,
                              hipStream_t stream) {
    const float* x   = (const float*)d_in[0];
    const int*   ei  = (const int*)d_in[1];
    const int*   bat = (const int*)d_in[2];
    const float* W1  = (const float*)d_in[3];
    const float* b1  = (const float*)d_in[4];
    const float* g1  = (const float*)d_in[5];
    const float* bt1 = (const float*)d_in[6];
    const float* W2  = (const float*)d_in[7];
    const float* b2  = (const float*)d_in[8];
    const float* g2  = (const float*)d_in[9];
    const float* bt2 = (const float*)d_in[10];
    const float* Wc1 = (const float*)d_in[11];
    const float* bc1 = (const float*)d_in[12];
    const float* Wc2 = (const float*)d_in[13];
    const float* bc2 = (const float*)d_in[14];
    float* out = (float*)d_out;

    const int* src = ei;
    const int* dst = ei + N_EDGES;

    char* ws = (char*)d_ws;
    size_t off = 0;
    auto alloc = [&](size_t bytes) -> void* {
        void* p = ws + off;
        off += (bytes + 255) & ~(size_t)255;
        return p;
    };
    // --- zero zone (single memset) ---
    int*   deg   = (int*)alloc(N_NODES * sizeof(int));
    int*   fill  = (int*)alloc(N_NODES * sizeof(int));
    float* stats = (float*)alloc(6 * 2 * D * sizeof(float));  // [layer][bn1/bn2][2*D]
    float* ro    = (float*)alloc((size_t)NUM_GRAPHS * NLAYERS * D * sizeof(float));
    size_t zero_bytes = off;
    // --- rest ---
    int*   gp    = (int*)alloc((NUM_GRAPHS + 1) * sizeof(int));
    int*   bsum  = (int*)alloc(256 * sizeof(int));
    int*   rowp  = (int*)alloc((N_NODES + 1) * sizeof(int));
    int*   csr   = (int*)alloc(N_EDGES * sizeof(int));
    const size_t NBH = (size_t)N_NODES * D * sizeof(unsigned short);
    unsigned short* xb   = (unsigned short*)alloc(NBH);
    unsigned short* bufA = (unsigned short*)alloc(NBH);
    unsigned short* bufB = (unsigned short*)alloc(NBH);
    unsigned short* bufC = (unsigned short*)alloc(NBH);
    short8* Wb   = (short8*)alloc(6 * 32 * 64 * sizeof(short8));

    hipMemsetAsync(ws, 0, zero_bytes, stream);
    hipMemsetAsync(gp, 0x7f, (NUM_GRAPHS + 1) * sizeof(int), stream);

    k_pre<<<3125, 256, 0, stream>>>(dst, bat, x, W1, W2, deg, gp, (us4*)xb, Wb);
    k_s1<<<196, 256, 0, stream>>>(deg, bsum);
    k_s2<<<1, 256, 0, stream>>>(bsum, gp, rowp);
    k_s3<<<196, 256, 0, stream>>>(deg, bsum, rowp);
    k_scatter<<<3125, 256, 0, stream>>>(src, dst, rowp, fill, csr);

    const int agg_grid  = (N_NODES * 32 + 255) / 256;
    const int gemm_grid = (N_NODES + 63) / 64;
    const unsigned short* H = xb;
    for (int i = 0; i < NLAYERS; i++) {
        float* st1 = stats + (size_t)(2 * i) * 2 * D;
        float* st2 = stats + (size_t)(2 * i + 1) * 2 * D;
        float* st2p = stats + (size_t)(2 * i - 1) * 2 * D;  // prev layer bn2
        if (i == 0)
            k_agg<false><<<agg_grid, 256, 0, stream>>>((const us4*)H, nullptr, nullptr, nullptr,
                                                       rowp, csr, (us4*)bufA);
        else
            k_agg<true><<<agg_grid, 256, 0, stream>>>((const us4*)H, st2p, g2 + (i - 1) * D,
                                                      bt2 + (i - 1) * D, rowp, csr, (us4*)bufA);
        k_gemm<false><<<gemm_grid, 256, 0, stream>>>(bufA, Wb + (size_t)i * 2048, b1 + i * D,
                                                     nullptr, nullptr, nullptr, bufB, st1, N_NODES);
        k_gemm<true><<<gemm_grid, 256, 0, stream>>>(bufB, Wb + (size_t)(3 + i) * 2048, b2 + i * D,
                                                    st1, g1 + i * D, bt1 + i * D, bufC, st2, N_NODES);
        k_readout<<<196, 256, 0, stream>>>((const unsigned int*)bufC, st2, g2 + i * D, bt2 + i * D,
                                           gp, bat, ro, i);
        H = bufC;
    }
    k_cls<<<NUM_GRAPHS, 128, 0, stream>>>(ro, Wc1, bc1, Wc2, bc2, out);
}

// Round 4
// 486.936 us; speedup vs baseline: 2.4874x; 1.0589x over previous
//
#include <hip/hip_runtime.h>

#define N_NODES 50000
#define N_EDGES 800000
#define D 128
#define NLAYERS 3
#define N_CLASSES 10
#define NUM_GRAPHS 256
#define BN_EPS 1e-5f

typedef __attribute__((ext_vector_type(4))) float f4;
typedef __attribute__((ext_vector_type(2))) float f2;
typedef __attribute__((ext_vector_type(8))) short short8;
typedef __attribute__((ext_vector_type(4))) unsigned short us4;
typedef __attribute__((ext_vector_type(8))) unsigned short us8;

__device__ inline float b2f(unsigned short u) {
    unsigned int i = ((unsigned int)u) << 16;
    return __builtin_bit_cast(float, i);
}
__device__ inline unsigned short f2b(float f) {
    unsigned int u = __builtin_bit_cast(unsigned int, f);
    unsigned int r = (u + 0x7FFFu + ((u >> 16) & 1u)) >> 16;  // RNE
    return (unsigned short)r;
}

// BN coef into LDS: ac[0..127]=a, ac[128..255]=c  (z_norm = a*z + c)
__device__ inline void coef_to_lds(const float* __restrict__ stats,
                                   const float* __restrict__ g,
                                   const float* __restrict__ bt,
                                   float* ac_sm, int tid) {
    if (tid < D) {
        float mu = stats[tid] * (1.0f / N_NODES);
        float var = stats[D + tid] * (1.0f / N_NODES) - mu * mu;
        float inv = rsqrtf(var + BN_EPS);
        float a = g[tid] * inv;
        ac_sm[tid] = a;
        ac_sm[D + tid] = bt[tid] - mu * a;
    }
}

// ---------------- graph build: histogram with saved slot ----------------
// grid 3125 x 256 = 800000 threads exactly

__global__ __launch_bounds__(256) void k_hist(const int* __restrict__ dst,
                                              const int* __restrict__ bat,
                                              int* __restrict__ deg,
                                              int* __restrict__ pos,
                                              int* __restrict__ gp) {
    int e = blockIdx.x * 256 + threadIdx.x;
    int d = dst[e];
    pos[e] = atomicAdd(&deg[d], 1);
    if (e < N_NODES) atomicMin(&gp[bat[e]], e);
}

// ---------------- streaming prep: xcast + wprep ----------------

__global__ __launch_bounds__(256) void k_xw(const float* __restrict__ x,
                                            const float* __restrict__ W1,
                                            const float* __restrict__ W2,
                                            us4* __restrict__ xb,
                                            short8* __restrict__ Wb) {
    int gid = blockIdx.x * 256 + threadIdx.x;
    const f4* xf = (const f4*)x;
#pragma unroll
    for (int rep = 0; rep < 2; rep++) {
        int i = gid + rep * 800000;  // 2*800000 == N_NODES*D/4
        f4 v = xf[i];
        us4 o;
        o[0] = f2b(v.x); o[1] = f2b(v.y); o[2] = f2b(v.z); o[3] = f2b(v.w);
        xb[i] = o;
    }
    if (gid < 6 * 32 * 64) {
        int m = gid >> 11;
        int f = (gid >> 6) & 31;
        int l = gid & 63;
        int ct = f >> 2, ks = f & 3;
        int n = ct * 16 + (l & 15);
        int k0 = ks * 32 + (l >> 4) * 8;
        const float* Wsrc = (m < 3) ? (W1 + (size_t)m * D * D) : (W2 + (size_t)(m - 3) * D * D);
        short8 o;
#pragma unroll
        for (int j = 0; j < 8; j++) o[j] = (short)f2b(Wsrc[(size_t)(k0 + j) * D + n]);
        Wb[gid] = o;
    }
}

// ---------------- hierarchical scan ----------------

__global__ void k_s1(const int* __restrict__ deg, int* __restrict__ bsum) {
    __shared__ int sm[256];
    int t = threadIdx.x;
    int i = blockIdx.x * 256 + t;
    int v = (i < N_NODES) ? deg[i] : 0;
    sm[t] = v;
    __syncthreads();
    for (int off = 128; off > 0; off >>= 1) {
        if (t < off) sm[t] += sm[t + off];
        __syncthreads();
    }
    if (t == 0) bsum[blockIdx.x] = sm[0];
}

__global__ void k_s2(int* __restrict__ bsum, int* __restrict__ gp, int* __restrict__ rowp) {
    __shared__ int sm[256];
    __shared__ int gm[257];
    int t = threadIdx.x;  // 256
    int v = (t < 196) ? bsum[t] : 0;
    sm[t] = v;
    gm[t] = min(gp[t], N_NODES);
    if (t == 0) gm[256] = N_NODES;
    __syncthreads();
    for (int off = 1; off < 256; off <<= 1) {
        int u = (t >= off) ? sm[t - off] : 0;
        __syncthreads();
        sm[t] += u;
        __syncthreads();
    }
    if (t < 196) bsum[t] = sm[t] - v;
    if (t == 195) rowp[N_NODES] = sm[t];
    for (int off = 1; off <= 256; off <<= 1) {
        int u = (t + off <= 256) ? gm[t + off] : N_NODES;
        __syncthreads();
        gm[t] = min(gm[t], u);
        __syncthreads();
    }
    gp[t] = gm[t];
    if (t == 0) gp[256] = N_NODES;
}

__global__ void k_s3(const int* __restrict__ deg, const int* __restrict__ bsum,
                     int* __restrict__ rowp) {
    __shared__ int sm[256];
    int t = threadIdx.x;
    int i = blockIdx.x * 256 + t;
    int v = (i < N_NODES) ? deg[i] : 0;
    sm[t] = v;
    __syncthreads();
    for (int off = 1; off < 256; off <<= 1) {
        int u = (t >= off) ? sm[t - off] : 0;
        __syncthreads();
        sm[t] += u;
        __syncthreads();
    }
    if (i < N_NODES) rowp[i] = bsum[blockIdx.x] + sm[t] - v;
}

// atomic-free scatter using saved slots
__global__ __launch_bounds__(256) void k_scatter(const int* __restrict__ src,
                                                 const int* __restrict__ dst,
                                                 const int* __restrict__ pos,
                                                 const int* __restrict__ rowp,
                                                 int* __restrict__ csr) {
    int e = blockIdx.x * 256 + threadIdx.x;
    csr[rowp[dst[e]] + pos[e]] = src[e];
}

// ---------------- aggregation: 16 lanes/node, us8 loads, fp32 accum ----------------
// u[n] = t(h[n]) + sum_{j->n} t(h[j]),  t = identity or relu(a*x+c)
// grid 3125 x 256 = 800000 = 50000 nodes * 16 lanes exactly

template <bool APPLY_T>
__global__ __launch_bounds__(256) void k_agg(const us8* __restrict__ H,
                                             const float* __restrict__ stats,
                                             const float* __restrict__ g,
                                             const float* __restrict__ bt,
                                             const int* __restrict__ rowp,
                                             const int* __restrict__ csr,
                                             us8* __restrict__ U) {
    __shared__ float ac_sm[2 * D];
    int tid = threadIdx.x;
    if (APPLY_T) {
        coef_to_lds(stats, g, bt, ac_sm, tid);
        __syncthreads();
    }
    int gid = blockIdx.x * 256 + tid;
    int node = gid >> 4;
    int lane = tid & 15;
    float av[8], cv[8];
    if (APPLY_T) {
#pragma unroll
        for (int i = 0; i < 8; i++) {
            av[i] = ac_sm[lane * 8 + i];
            cv[i] = ac_sm[D + lane * 8 + i];
        }
    }
    float s[8] = {0.f, 0.f, 0.f, 0.f, 0.f, 0.f, 0.f, 0.f};
    auto accum = [&](us8 v) {
#pragma unroll
        for (int i = 0; i < 8; i++) {
            float f = b2f(v[i]);
            if (APPLY_T) f = fmaxf(f * av[i] + cv[i], 0.f);
            s[i] += f;
        }
    };
    accum(H[(size_t)node * 16 + lane]);  // self
    int beg = rowp[node], end = rowp[node + 1];
    int j = beg;
    for (; j + 4 <= end; j += 4) {
        int i0 = csr[j], i1 = csr[j + 1], i2 = csr[j + 2], i3 = csr[j + 3];
        us8 v0 = H[(size_t)i0 * 16 + lane];
        us8 v1 = H[(size_t)i1 * 16 + lane];
        us8 v2 = H[(size_t)i2 * 16 + lane];
        us8 v3 = H[(size_t)i3 * 16 + lane];
        accum(v0); accum(v1); accum(v2); accum(v3);
    }
    for (; j < end; j++) accum(H[(size_t)csr[j] * 16 + lane]);
    us8 o;
#pragma unroll
    for (int i = 0; i < 8; i++) o[i] = f2b(s[i]);
    U[(size_t)node * 16 + lane] = o;
}

// ---------------- MFMA GEMM: Z = t(A) @ W + bias, fused column stats ----------------

template <bool TRANS>
__global__ __launch_bounds__(256) void k_gemm(const unsigned short* __restrict__ A,
                                              const short8* __restrict__ Wb,
                                              const float* __restrict__ bias,
                                              const float* __restrict__ stats_in,
                                              const float* __restrict__ g,
                                              const float* __restrict__ bt,
                                              unsigned short* __restrict__ Z,
                                              float* __restrict__ stats_out, int M) {
    __shared__ float lds_s[D], lds_q[D];
    __shared__ float ac_sm[2 * D];
    int tid = threadIdx.x;
    if (tid < D) { lds_s[tid] = 0.f; lds_q[tid] = 0.f; }
    if (TRANS) coef_to_lds(stats_in, g, bt, ac_sm, tid);
    int w = tid >> 6, l = tid & 63;
    int lr = l & 15, lg = l >> 4;
    int rowb = blockIdx.x * 64 + w * 16;
    int arow = rowb + lr;
    int arow_c = arow < M ? arow : M - 1;
    f4 acc[8];
#pragma unroll
    for (int ct = 0; ct < 8; ct++) {
        float bv = bias[ct * 16 + lr];
        acc[ct].x = bv; acc[ct].y = bv; acc[ct].z = bv; acc[ct].w = bv;
    }
    __syncthreads();

#pragma unroll
    for (int ks = 0; ks < 4; ks++) {
        short8 a;
        if (!TRANS) {
            a = *(const short8*)(A + (size_t)arow_c * D + ks * 32 + lg * 8);
        } else {
            int k0 = ks * 32 + lg * 8;
            const unsigned short* ap = A + (size_t)arow_c * D + k0;
            us4 v0 = *(const us4*)ap;
            us4 v1 = *(const us4*)(ap + 4);
            f4 a0 = *(const f4*)&ac_sm[k0];
            f4 a1 = *(const f4*)&ac_sm[k0 + 4];
            f4 c0 = *(const f4*)&ac_sm[D + k0];
            f4 c1 = *(const f4*)&ac_sm[D + k0 + 4];
            a[0] = (short)f2b(fmaxf(b2f(v0[0]) * a0.x + c0.x, 0.f));
            a[1] = (short)f2b(fmaxf(b2f(v0[1]) * a0.y + c0.y, 0.f));
            a[2] = (short)f2b(fmaxf(b2f(v0[2]) * a0.z + c0.z, 0.f));
            a[3] = (short)f2b(fmaxf(b2f(v0[3]) * a0.w + c0.w, 0.f));
            a[4] = (short)f2b(fmaxf(b2f(v1[0]) * a1.x + c1.x, 0.f));
            a[5] = (short)f2b(fmaxf(b2f(v1[1]) * a1.y + c1.y, 0.f));
            a[6] = (short)f2b(fmaxf(b2f(v1[2]) * a1.z + c1.z, 0.f));
            a[7] = (short)f2b(fmaxf(b2f(v1[3]) * a1.w + c1.w, 0.f));
        }
#pragma unroll
        for (int ct = 0; ct < 8; ct++) {
            short8 b = Wb[(ct * 4 + ks) * 64 + l];
            acc[ct] = __builtin_amdgcn_mfma_f32_16x16x32_bf16(a, b, acc[ct], 0, 0, 0);
        }
    }

    float vm[4];
#pragma unroll
    for (int r = 0; r < 4; r++) vm[r] = (rowb + lg * 4 + r) < M ? 1.f : 0.f;
#pragma unroll
    for (int ct = 0; ct < 8; ct++) {
        float s = 0.f, q = 0.f;
#pragma unroll
        for (int r = 0; r < 4; r++) {
            float v = acc[ct][r];
            s += v * vm[r];
            q += v * v * vm[r];
            int rd = rowb + lg * 4 + r;
            if (rd < M) Z[(size_t)rd * D + ct * 16 + lr] = f2b(v);
        }
        s += __shfl_xor(s, 16);
        s += __shfl_xor(s, 32);
        q += __shfl_xor(q, 16);
        q += __shfl_xor(q, 32);
        if (lg == 0) {
            atomicAdd(&lds_s[ct * 16 + lr], s);
            atomicAdd(&lds_q[ct * 16 + lr], q);
        }
    }
    __syncthreads();
    if (tid < D) {
        atomicAdd(&stats_out[tid], lds_s[tid]);
        atomicAdd(&stats_out[D + tid], lds_q[tid]);
    }
}

// ---------------- readout ----------------

__global__ __launch_bounds__(256) void k_readout(const unsigned int* __restrict__ Zb,
                                                 const float* __restrict__ stats,
                                                 const float* __restrict__ g,
                                                 const float* __restrict__ bt,
                                                 const int* __restrict__ gp,
                                                 const int* __restrict__ batch,
                                                 float* __restrict__ ro, int layer) {
    __shared__ f2 sm[256];
    __shared__ float ac_sm[2 * D];
    int tid = threadIdx.x;
    coef_to_lds(stats, g, bt, ac_sm, tid);
    __syncthreads();
    int n0 = blockIdx.x * 256;
    int n1 = n0 + 256; if (n1 > N_NODES) n1 = N_NODES;
    int g_lo = batch[n0], g_hi = batch[n1 - 1];
    int grp = tid >> 6, cw = tid & 63;
    float a0 = ac_sm[2 * cw], a1 = ac_sm[2 * cw + 1];
    float c0 = ac_sm[D + 2 * cw], c1 = ac_sm[D + 2 * cw + 1];
    for (int gg = g_lo; gg <= g_hi; gg++) {
        int beg = gp[gg]; if (beg < n0) beg = n0;
        int end = gp[gg + 1]; if (end > n1) end = n1;
        f2 acc; acc.x = 0.f; acc.y = 0.f;
        for (int r = beg + grp; r < end; r += 4) {
            unsigned int v = Zb[(size_t)r * 64 + cw];
            float x0 = b2f((unsigned short)(v & 0xFFFFu));
            float x1 = b2f((unsigned short)(v >> 16));
            acc.x += fmaxf(x0 * a0 + c0, 0.f);
            acc.y += fmaxf(x1 * a1 + c1, 0.f);
        }
        sm[tid] = acc;
        __syncthreads();
        if (tid < 64) {
            f2 t = sm[tid];
            t.x += sm[tid + 64].x + sm[tid + 128].x + sm[tid + 192].x;
            t.y += sm[tid + 64].y + sm[tid + 128].y + sm[tid + 192].y;
            atomicAdd(&ro[(size_t)gg * (NLAYERS * D) + layer * D + 2 * cw], t.x);
            atomicAdd(&ro[(size_t)gg * (NLAYERS * D) + layer * D + 2 * cw + 1], t.y);
        }
        __syncthreads();
    }
}

// ---------------- classifier ----------------

__global__ void k_cls(const float* __restrict__ ro, const float* __restrict__ Wc1,
                      const float* __restrict__ bc1, const float* __restrict__ Wc2,
                      const float* __restrict__ bc2, float* __restrict__ out) {
    __shared__ float r_sm[NLAYERS * D];
    __shared__ float h_sm[D];
    int g = blockIdx.x;
    int t = threadIdx.x;  // 128
    for (int i = t; i < NLAYERS * D; i += D) r_sm[i] = ro[(size_t)g * (NLAYERS * D) + i];
    __syncthreads();
    float acc = bc1[t];
    for (int k = 0; k < NLAYERS * D; k++) acc += r_sm[k] * Wc1[(size_t)k * D + t];
    h_sm[t] = fmaxf(acc, 0.f);
    __syncthreads();
    if (t < N_CLASSES) {
        float o = bc2[t];
        for (int k = 0; k < D; k++) o += h_sm[k] * Wc2[k * N_CLASSES + t];
        out[g * N_CLASSES + t] = o;
    }
}

// ---------------- launch ----------------

extern "C" void kernel_launch(void* const* d_in, const int* in_sizes, int n_in,
                              void* d_out, int out_size, void* d_ws, size_t ws_size,
                              hipStream_t stream) {
    const float* x   = (const float*)d_in[0];
    const int*   ei  = (const int*)d_in[1];
    const int*   bat = (const int*)d_in[2];
    const float* W1  = (const float*)d_in[3];
    const float* b1  = (const float*)d_in[4];
    const float* g1  = (const float*)d_in[5];
    const float* bt1 = (const float*)d_in[6];
    const float* W2  = (const float*)d_in[7];
    const float* b2  = (const float*)d_in[8];
    const float* g2  = (const float*)d_in[9];
    const float* bt2 = (const float*)d_in[10];
    const float* Wc1 = (const float*)d_in[11];
    const float* bc1 = (const float*)d_in[12];
    const float* Wc2 = (const float*)d_in[13];
    const float* bc2 = (const float*)d_in[14];
    float* out = (float*)d_out;

    const int* src = ei;
    const int* dst = ei + N_EDGES;

    char* ws = (char*)d_ws;
    size_t off = 0;
    auto alloc = [&](size_t bytes) -> void* {
        void* p = ws + off;
        off += (bytes + 255) & ~(size_t)255;
        return p;
    };
    // --- zero zone (single memset) ---
    int*   deg   = (int*)alloc(N_NODES * sizeof(int));
    float* stats = (float*)alloc(6 * 2 * D * sizeof(float));  // [layer][bn1/bn2][2*D]
    float* ro    = (float*)alloc((size_t)NUM_GRAPHS * NLAYERS * D * sizeof(float));
    size_t zero_bytes = off;
    // --- rest ---
    int*   gp    = (int*)alloc((NUM_GRAPHS + 1) * sizeof(int));
    int*   bsum  = (int*)alloc(256 * sizeof(int));
    int*   rowp  = (int*)alloc((N_NODES + 1) * sizeof(int));
    int*   pos   = (int*)alloc(N_EDGES * sizeof(int));
    int*   csr   = (int*)alloc(N_EDGES * sizeof(int));
    const size_t NBH = (size_t)N_NODES * D * sizeof(unsigned short);
    unsigned short* xb   = (unsigned short*)alloc(NBH);
    unsigned short* bufA = (unsigned short*)alloc(NBH);
    unsigned short* bufB = (unsigned short*)alloc(NBH);
    unsigned short* bufC = (unsigned short*)alloc(NBH);
    short8* Wb   = (short8*)alloc(6 * 32 * 64 * sizeof(short8));

    hipMemsetAsync(ws, 0, zero_bytes, stream);
    hipMemsetAsync(gp, 0x7f, (NUM_GRAPHS + 1) * sizeof(int), stream);

    k_hist<<<3125, 256, 0, stream>>>(dst, bat, deg, pos, gp);
    k_xw<<<3125, 256, 0, stream>>>(x, W1, W2, (us4*)xb, Wb);
    k_s1<<<196, 256, 0, stream>>>(deg, bsum);
    k_s2<<<1, 256, 0, stream>>>(bsum, gp, rowp);
    k_s3<<<196, 256, 0, stream>>>(deg, bsum, rowp);
    k_scatter<<<3125, 256, 0, stream>>>(src, dst, pos, rowp, csr);

    const int gemm_grid = (N_NODES + 63) / 64;
    const unsigned short* H = xb;
    for (int i = 0; i < NLAYERS; i++) {
        float* st1 = stats + (size_t)(2 * i) * 2 * D;
        float* st2 = stats + (size_t)(2 * i + 1) * 2 * D;
        float* st2p = stats + (size_t)(2 * i - 1) * 2 * D;  // prev layer bn2
        if (i == 0)
            k_agg<false><<<3125, 256, 0, stream>>>((const us8*)H, nullptr, nullptr, nullptr,
                                                   rowp, csr, (us8*)bufA);
        else
            k_agg<true><<<3125, 256, 0, stream>>>((const us8*)H, st2p, g2 + (i - 1) * D,
                                                  bt2 + (i - 1) * D, rowp, csr, (us8*)bufA);
        k_gemm<false><<<gemm_grid, 256, 0, stream>>>(bufA, Wb + (size_t)i * 2048, b1 + i * D,
                                                     nullptr, nullptr, nullptr, bufB, st1, N_NODES);
        k_gemm<true><<<gemm_grid, 256, 0, stream>>>(bufB, Wb + (size_t)(3 + i) * 2048, b2 + i * D,
                                                    st1, g1 + i * D, bt1 + i * D, bufC, st2, N_NODES);
        k_readout<<<196, 256, 0, stream>>>((const unsigned int*)bufC, st2, g2 + i * D, bt2 + i * D,
                                           gp, bat, ro, i);
        H = bufC;
    }
    k_cls<<<NUM_GRAPHS, 128, 0, stream>>>(ro, Wc1, bc1, Wc2, bc2, out);
}

// Round 5
// 343.132 us; speedup vs baseline: 3.5298x; 1.4191x over previous
//
#include <hip/hip_runtime.h>

#define N_NODES 50000
#define N_EDGES 800000
#define D 128
#define NLAYERS 3
#define N_CLASSES 10
#define NUM_GRAPHS 256
#define BN_EPS 1e-5f

#define CHUNKS 64
#define CHSIZE 12500   // CHUNKS*CHSIZE == N_EDGES
#define RANGES 4
#define RSIZE 12500    // RANGES*RSIZE == N_NODES
#define SBANKS 8       // stats replication banks

typedef __attribute__((ext_vector_type(4))) float f4;
typedef __attribute__((ext_vector_type(2))) float f2;
typedef __attribute__((ext_vector_type(8))) short short8;
typedef __attribute__((ext_vector_type(4))) unsigned short us4;
typedef __attribute__((ext_vector_type(8))) unsigned short us8;

__device__ inline float b2f(unsigned short u) {
    unsigned int i = ((unsigned int)u) << 16;
    return __builtin_bit_cast(float, i);
}
__device__ inline unsigned short f2b(float f) {
    unsigned int u = __builtin_bit_cast(unsigned int, f);
    unsigned int r = (u + 0x7FFFu + ((u >> 16) & 1u)) >> 16;  // RNE
    return (unsigned short)r;
}

// BN coef into LDS from banked stats: ac[0..127]=a, ac[128..255]=c (z_norm = a*z + c)
__device__ inline void coef_to_lds(const float* __restrict__ stats,
                                   const float* __restrict__ g,
                                   const float* __restrict__ bt,
                                   float* ac_sm, int tid) {
    if (tid < D) {
        float s = 0.f, q = 0.f;
#pragma unroll
        for (int b = 0; b < SBANKS; b++) {
            s += stats[b * 2 * D + tid];
            q += stats[b * 2 * D + D + tid];
        }
        float mu = s * (1.0f / N_NODES);
        float var = q * (1.0f / N_NODES) - mu * mu;
        float inv = rsqrtf(var + BN_EPS);
        float a = g[tid] * inv;
        ac_sm[tid] = a;
        ac_sm[D + tid] = bt[tid] - mu * a;
    }
}

// ---------------- graph build: LDS-partitioned histogram ----------------
// grid (CHUNKS, RANGES) x 256. Each block: chunk c of edges, node range r.

__global__ __launch_bounds__(256) void k_ph(const int* __restrict__ dst,
                                            int* __restrict__ pos,
                                            int* __restrict__ ph) {
    __shared__ int h[RSIZE];
    int c = blockIdx.x, r = blockIdx.y;
    int t = threadIdx.x;
    for (int i = t; i < RSIZE; i += 256) h[i] = 0;
    __syncthreads();
    int base = c * CHSIZE;
    int lo = r * RSIZE;
    for (int j = t; j < CHSIZE; j += 256) {
        int d = dst[base + j] - lo;
        if ((unsigned)d < RSIZE) pos[base + j] = atomicAdd(&h[d], 1);
    }
    __syncthreads();
    int* outp = ph + (size_t)c * N_NODES + lo;
    for (int i = t; i < RSIZE; i += 256) outp[i] = h[i];
}

// deg[b] = sum_c ph[c][b]; ph[c][b] <- exclusive chunk prefix
__global__ __launch_bounds__(256) void k_merge(int* __restrict__ ph, int* __restrict__ deg) {
    int b = blockIdx.x * 256 + threadIdx.x;
    if (b >= N_NODES) return;
    int s = 0;
#pragma unroll 4
    for (int c = 0; c < CHUNKS; c++) {
        int v = ph[(size_t)c * N_NODES + b];
        ph[(size_t)c * N_NODES + b] = s;
        s += v;
    }
    deg[b] = s;
}

// ---------------- streaming prep: xcast + wprep ----------------

__global__ __launch_bounds__(256) void k_xw(const float* __restrict__ x,
                                            const float* __restrict__ W1,
                                            const float* __restrict__ W2,
                                            us4* __restrict__ xb,
                                            short8* __restrict__ Wb) {
    int gid = blockIdx.x * 256 + threadIdx.x;
    const f4* xf = (const f4*)x;
#pragma unroll
    for (int rep = 0; rep < 2; rep++) {
        int i = gid + rep * 800000;  // 2*800000 == N_NODES*D/4
        f4 v = xf[i];
        us4 o;
        o[0] = f2b(v.x); o[1] = f2b(v.y); o[2] = f2b(v.z); o[3] = f2b(v.w);
        xb[i] = o;
    }
    if (gid < 6 * 32 * 64) {
        int m = gid >> 11;
        int f = (gid >> 6) & 31;
        int l = gid & 63;
        int ct = f >> 2, ks = f & 3;
        int n = ct * 16 + (l & 15);
        int k0 = ks * 32 + (l >> 4) * 8;
        const float* Wsrc = (m < 3) ? (W1 + (size_t)m * D * D) : (W2 + (size_t)(m - 3) * D * D);
        short8 o;
#pragma unroll
        for (int j = 0; j < 8; j++) o[j] = (short)f2b(Wsrc[(size_t)(k0 + j) * D + n]);
        Wb[gid] = o;
    }
}

// ---------------- scan + graph boundaries (no atomics) ----------------

__global__ void k_s1(const int* __restrict__ deg, const int* __restrict__ bat,
                     int* __restrict__ bsum, int* __restrict__ gp) {
    __shared__ int sm[256];
    int t = threadIdx.x;
    int i = blockIdx.x * 256 + t;
    int v = (i < N_NODES) ? deg[i] : 0;
    sm[t] = v;
    __syncthreads();
    for (int off = 128; off > 0; off >>= 1) {
        if (t < off) sm[t] += sm[t + off];
        __syncthreads();
    }
    if (t == 0) bsum[blockIdx.x] = sm[0];
    // graph boundaries from sorted batch
    if (i < N_NODES) {
        int b = bat[i];
        int prev = (i == 0) ? -1 : bat[i - 1];
        for (int g = prev + 1; g <= b; g++) gp[g] = i;
        if (i == N_NODES - 1)
            for (int g = b + 1; g <= NUM_GRAPHS; g++) gp[g] = N_NODES;
    }
}

__global__ void k_s2(int* __restrict__ bsum, int* __restrict__ rowp) {
    __shared__ int sm[256];
    int t = threadIdx.x;  // 256
    int v = (t < 196) ? bsum[t] : 0;
    sm[t] = v;
    __syncthreads();
    for (int off = 1; off < 256; off <<= 1) {
        int u = (t >= off) ? sm[t - off] : 0;
        __syncthreads();
        sm[t] += u;
        __syncthreads();
    }
    if (t < 196) bsum[t] = sm[t] - v;
    if (t == 195) rowp[N_NODES] = sm[t];
}

__global__ void k_s3(const int* __restrict__ deg, const int* __restrict__ bsum,
                     int* __restrict__ rowp) {
    __shared__ int sm[256];
    int t = threadIdx.x;
    int i = blockIdx.x * 256 + t;
    int v = (i < N_NODES) ? deg[i] : 0;
    sm[t] = v;
    __syncthreads();
    for (int off = 1; off < 256; off <<= 1) {
        int u = (t >= off) ? sm[t - off] : 0;
        __syncthreads();
        sm[t] += u;
        __syncthreads();
    }
    if (i < N_NODES) rowp[i] = bsum[blockIdx.x] + sm[t] - v;
}

// fully atomic-free scatter
__global__ __launch_bounds__(256) void k_scatter(const int* __restrict__ src,
                                                 const int* __restrict__ dst,
                                                 const int* __restrict__ pos,
                                                 const int* __restrict__ ph,
                                                 const int* __restrict__ rowp,
                                                 int* __restrict__ csr) {
    int e = blockIdx.x * 256 + threadIdx.x;
    int c = e / CHSIZE;
    int d = dst[e];
    csr[rowp[d] + ph[(size_t)c * N_NODES + d] + pos[e]] = src[e];
}

// ---------------- aggregation: 16 lanes/node, us8 loads, fp32 accum ----------------

template <bool APPLY_T>
__global__ __launch_bounds__(256) void k_agg(const us8* __restrict__ H,
                                             const float* __restrict__ stats,
                                             const float* __restrict__ g,
                                             const float* __restrict__ bt,
                                             const int* __restrict__ rowp,
                                             const int* __restrict__ csr,
                                             us8* __restrict__ U) {
    __shared__ float ac_sm[2 * D];
    int tid = threadIdx.x;
    if (APPLY_T) {
        coef_to_lds(stats, g, bt, ac_sm, tid);
        __syncthreads();
    }
    int gid = blockIdx.x * 256 + tid;
    int node = gid >> 4;
    int lane = tid & 15;
    float av[8], cv[8];
    if (APPLY_T) {
#pragma unroll
        for (int i = 0; i < 8; i++) {
            av[i] = ac_sm[lane * 8 + i];
            cv[i] = ac_sm[D + lane * 8 + i];
        }
    }
    float s[8] = {0.f, 0.f, 0.f, 0.f, 0.f, 0.f, 0.f, 0.f};
    auto accum = [&](us8 v) {
#pragma unroll
        for (int i = 0; i < 8; i++) {
            float f = b2f(v[i]);
            if (APPLY_T) f = fmaxf(f * av[i] + cv[i], 0.f);
            s[i] += f;
        }
    };
    accum(H[(size_t)node * 16 + lane]);  // self
    int beg = rowp[node], end = rowp[node + 1];
    int j = beg;
    for (; j + 4 <= end; j += 4) {
        int i0 = csr[j], i1 = csr[j + 1], i2 = csr[j + 2], i3 = csr[j + 3];
        us8 v0 = H[(size_t)i0 * 16 + lane];
        us8 v1 = H[(size_t)i1 * 16 + lane];
        us8 v2 = H[(size_t)i2 * 16 + lane];
        us8 v3 = H[(size_t)i3 * 16 + lane];
        accum(v0); accum(v1); accum(v2); accum(v3);
    }
    for (; j < end; j++) accum(H[(size_t)csr[j] * 16 + lane]);
    us8 o;
#pragma unroll
    for (int i = 0; i < 8; i++) o[i] = f2b(s[i]);
    U[(size_t)node * 16 + lane] = o;
}

// ---------------- MFMA GEMM: 128 rows/block, fused banked column stats ----------------

template <bool TRANS>
__global__ __launch_bounds__(256) void k_gemm(const unsigned short* __restrict__ A,
                                              const short8* __restrict__ Wb,
                                              const float* __restrict__ bias,
                                              const float* __restrict__ stats_in,
                                              const float* __restrict__ g,
                                              const float* __restrict__ bt,
                                              unsigned short* __restrict__ Z,
                                              float* __restrict__ stats_out, int M) {
    __shared__ float lds_s[D], lds_q[D];
    __shared__ float ac_sm[2 * D];
    int tid = threadIdx.x;
    if (tid < D) { lds_s[tid] = 0.f; lds_q[tid] = 0.f; }
    if (TRANS) coef_to_lds(stats_in, g, bt, ac_sm, tid);
    int w = tid >> 6, l = tid & 63;
    int lr = l & 15, lg = l >> 4;
    int rowb0 = blockIdx.x * 128 + w * 32;
    f4 acc[2][8];
#pragma unroll
    for (int ct = 0; ct < 8; ct++) {
        float bv = bias[ct * 16 + lr];
#pragma unroll
        for (int rt = 0; rt < 2; rt++) {
            acc[rt][ct].x = bv; acc[rt][ct].y = bv; acc[rt][ct].z = bv; acc[rt][ct].w = bv;
        }
    }
    __syncthreads();

#pragma unroll
    for (int ks = 0; ks < 4; ks++) {
        short8 a[2];
#pragma unroll
        for (int rt = 0; rt < 2; rt++) {
            int arow = rowb0 + rt * 16 + lr;
            int arow_c = arow < M ? arow : M - 1;
            if (!TRANS) {
                a[rt] = *(const short8*)(A + (size_t)arow_c * D + ks * 32 + lg * 8);
            } else {
                int k0 = ks * 32 + lg * 8;
                const unsigned short* ap = A + (size_t)arow_c * D + k0;
                us4 v0 = *(const us4*)ap;
                us4 v1 = *(const us4*)(ap + 4);
                f4 a0 = *(const f4*)&ac_sm[k0];
                f4 a1 = *(const f4*)&ac_sm[k0 + 4];
                f4 c0 = *(const f4*)&ac_sm[D + k0];
                f4 c1 = *(const f4*)&ac_sm[D + k0 + 4];
                a[rt][0] = (short)f2b(fmaxf(b2f(v0[0]) * a0.x + c0.x, 0.f));
                a[rt][1] = (short)f2b(fmaxf(b2f(v0[1]) * a0.y + c0.y, 0.f));
                a[rt][2] = (short)f2b(fmaxf(b2f(v0[2]) * a0.z + c0.z, 0.f));
                a[rt][3] = (short)f2b(fmaxf(b2f(v0[3]) * a0.w + c0.w, 0.f));
                a[rt][4] = (short)f2b(fmaxf(b2f(v1[0]) * a1.x + c1.x, 0.f));
                a[rt][5] = (short)f2b(fmaxf(b2f(v1[1]) * a1.y + c1.y, 0.f));
                a[rt][6] = (short)f2b(fmaxf(b2f(v1[2]) * a1.z + c1.z, 0.f));
                a[rt][7] = (short)f2b(fmaxf(b2f(v1[3]) * a1.w + c1.w, 0.f));
            }
        }
#pragma unroll
        for (int ct = 0; ct < 8; ct++) {
            short8 b = Wb[(ct * 4 + ks) * 64 + l];
            acc[0][ct] = __builtin_amdgcn_mfma_f32_16x16x32_bf16(a[0], b, acc[0][ct], 0, 0, 0);
            acc[1][ct] = __builtin_amdgcn_mfma_f32_16x16x32_bf16(a[1], b, acc[1][ct], 0, 0, 0);
        }
    }

#pragma unroll
    for (int ct = 0; ct < 8; ct++) {
        float s = 0.f, q = 0.f;
#pragma unroll
        for (int rt = 0; rt < 2; rt++) {
#pragma unroll
            for (int r = 0; r < 4; r++) {
                float v = acc[rt][ct][r];
                int rd = rowb0 + rt * 16 + lg * 4 + r;
                float m = rd < M ? 1.f : 0.f;
                s += v * m;
                q += v * v * m;
                if (rd < M) Z[(size_t)rd * D + ct * 16 + lr] = f2b(v);
            }
        }
        s += __shfl_xor(s, 16);
        s += __shfl_xor(s, 32);
        q += __shfl_xor(q, 16);
        q += __shfl_xor(q, 32);
        if (lg == 0) {
            atomicAdd(&lds_s[ct * 16 + lr], s);
            atomicAdd(&lds_q[ct * 16 + lr], q);
        }
    }
    __syncthreads();
    int bank = blockIdx.x & (SBANKS - 1);
    if (tid < D) {
        atomicAdd(&stats_out[bank * 2 * D + tid], lds_s[tid]);
        atomicAdd(&stats_out[bank * 2 * D + D + tid], lds_q[tid]);
    }
}

// ---------------- readout ----------------

__global__ __launch_bounds__(256) void k_readout(const unsigned int* __restrict__ Zb,
                                                 const float* __restrict__ stats,
                                                 const float* __restrict__ g,
                                                 const float* __restrict__ bt,
                                                 const int* __restrict__ gp,
                                                 const int* __restrict__ batch,
                                                 float* __restrict__ ro, int layer) {
    __shared__ f2 sm[256];
    __shared__ float ac_sm[2 * D];
    int tid = threadIdx.x;
    coef_to_lds(stats, g, bt, ac_sm, tid);
    __syncthreads();
    int n0 = blockIdx.x * 256;
    int n1 = n0 + 256; if (n1 > N_NODES) n1 = N_NODES;
    int g_lo = batch[n0], g_hi = batch[n1 - 1];
    int grp = tid >> 6, cw = tid & 63;
    float a0 = ac_sm[2 * cw], a1 = ac_sm[2 * cw + 1];
    float c0 = ac_sm[D + 2 * cw], c1 = ac_sm[D + 2 * cw + 1];
    for (int gg = g_lo; gg <= g_hi; gg++) {
        int beg = gp[gg]; if (beg < n0) beg = n0;
        int end = gp[gg + 1]; if (end > n1) end = n1;
        f2 acc; acc.x = 0.f; acc.y = 0.f;
        for (int r = beg + grp; r < end; r += 4) {
            unsigned int v = Zb[(size_t)r * 64 + cw];
            float x0 = b2f((unsigned short)(v & 0xFFFFu));
            float x1 = b2f((unsigned short)(v >> 16));
            acc.x += fmaxf(x0 * a0 + c0, 0.f);
            acc.y += fmaxf(x1 * a1 + c1, 0.f);
        }
        sm[tid] = acc;
        __syncthreads();
        if (tid < 64) {
            f2 t = sm[tid];
            t.x += sm[tid + 64].x + sm[tid + 128].x + sm[tid + 192].x;
            t.y += sm[tid + 64].y + sm[tid + 128].y + sm[tid + 192].y;
            atomicAdd(&ro[(size_t)gg * (NLAYERS * D) + layer * D + 2 * cw], t.x);
            atomicAdd(&ro[(size_t)gg * (NLAYERS * D) + layer * D + 2 * cw + 1], t.y);
        }
        __syncthreads();
    }
}

// ---------------- classifier ----------------

__global__ void k_cls(const float* __restrict__ ro, const float* __restrict__ Wc1,
                      const float* __restrict__ bc1, const float* __restrict__ Wc2,
                      const float* __restrict__ bc2, float* __restrict__ out) {
    __shared__ float r_sm[NLAYERS * D];
    __shared__ float h_sm[D];
    int g = blockIdx.x;
    int t = threadIdx.x;  // 128
    for (int i = t; i < NLAYERS * D; i += D) r_sm[i] = ro[(size_t)g * (NLAYERS * D) + i];
    __syncthreads();
    float acc = bc1[t];
    for (int k = 0; k < NLAYERS * D; k++) acc += r_sm[k] * Wc1[(size_t)k * D + t];
    h_sm[t] = fmaxf(acc, 0.f);
    __syncthreads();
    if (t < N_CLASSES) {
        float o = bc2[t];
        for (int k = 0; k < D; k++) o += h_sm[k] * Wc2[k * N_CLASSES + t];
        out[g * N_CLASSES + t] = o;
    }
}

// ---------------- launch ----------------

extern "C" void kernel_launch(void* const* d_in, const int* in_sizes, int n_in,
                              void* d_out, int out_size, void* d_ws, size_t ws_size,
                              hipStream_t stream) {
    const float* x   = (const float*)d_in[0];
    const int*   ei  = (const int*)d_in[1];
    const int*   bat = (const int*)d_in[2];
    const float* W1  = (const float*)d_in[3];
    const float* b1  = (const float*)d_in[4];
    const float* g1  = (const float*)d_in[5];
    const float* bt1 = (const float*)d_in[6];
    const float* W2  = (const float*)d_in[7];
    const float* b2  = (const float*)d_in[8];
    const float* g2  = (const float*)d_in[9];
    const float* bt2 = (const float*)d_in[10];
    const float* Wc1 = (const float*)d_in[11];
    const float* bc1 = (const float*)d_in[12];
    const float* Wc2 = (const float*)d_in[13];
    const float* bc2 = (const float*)d_in[14];
    float* out = (float*)d_out;

    const int* src = ei;
    const int* dst = ei + N_EDGES;

    char* ws = (char*)d_ws;
    size_t off = 0;
    auto alloc = [&](size_t bytes) -> void* {
        void* p = ws + off;
        off += (bytes + 255) & ~(size_t)255;
        return p;
    };
    // --- zero zone (single memset) ---
    float* stats = (float*)alloc(6 * SBANKS * 2 * D * sizeof(float));  // [6 BNs][banks][2D]
    float* ro    = (float*)alloc((size_t)NUM_GRAPHS * NLAYERS * D * sizeof(float));
    size_t zero_bytes = off;
    // --- rest (no init needed) ---
    int*   deg   = (int*)alloc(N_NODES * sizeof(int));
    int*   gp    = (int*)alloc((NUM_GRAPHS + 1) * sizeof(int));
    int*   bsum  = (int*)alloc(256 * sizeof(int));
    int*   rowp  = (int*)alloc((N_NODES + 1) * sizeof(int));
    int*   pos   = (int*)alloc(N_EDGES * sizeof(int));
    int*   csr   = (int*)alloc(N_EDGES * sizeof(int));
    const size_t NBH = (size_t)N_NODES * D * sizeof(unsigned short);
    unsigned short* xb   = (unsigned short*)alloc(NBH);
    unsigned short* bufA = (unsigned short*)alloc(NBH);
    unsigned short* bufB = (unsigned short*)alloc(NBH);
    unsigned short* bufC = (unsigned short*)alloc(NBH);
    short8* Wb   = (short8*)alloc(6 * 32 * 64 * sizeof(short8));
    // ph scratch aliases bufB (both exactly 12.8 MB); ph's last use (k_scatter)
    // precedes the first write of bufB (layer-0 gemm).
    int* ph = (int*)bufB;

    hipMemsetAsync(ws, 0, zero_bytes, stream);

    k_ph<<<dim3(CHUNKS, RANGES), 256, 0, stream>>>(dst, pos, ph);
    k_merge<<<196, 256, 0, stream>>>(ph, deg);
    k_xw<<<3125, 256, 0, stream>>>(x, W1, W2, (us4*)xb, Wb);
    k_s1<<<196, 256, 0, stream>>>(deg, bat, bsum, gp);
    k_s2<<<1, 256, 0, stream>>>(bsum, rowp);
    k_s3<<<196, 256, 0, stream>>>(deg, bsum, rowp);
    k_scatter<<<3125, 256, 0, stream>>>(src, dst, pos, ph, rowp, csr);

    const int gemm_grid = (N_NODES + 127) / 128;  // 391
    const unsigned short* H = xb;
    for (int i = 0; i < NLAYERS; i++) {
        float* st1 = stats + (size_t)(2 * i) * SBANKS * 2 * D;
        float* st2 = stats + (size_t)(2 * i + 1) * SBANKS * 2 * D;
        float* st2p = stats + (size_t)(2 * i - 1) * SBANKS * 2 * D;  // prev layer bn2
        if (i == 0)
            k_agg<false><<<3125, 256, 0, stream>>>((const us8*)H, nullptr, nullptr, nullptr,
                                                   rowp, csr, (us8*)bufA);
        else
            k_agg<true><<<3125, 256, 0, stream>>>((const us8*)H, st2p, g2 + (i - 1) * D,
                                                  bt2 + (i - 1) * D, rowp, csr, (us8*)bufA);
        k_gemm<false><<<gemm_grid, 256, 0, stream>>>(bufA, Wb + (size_t)i * 2048, b1 + i * D,
                                                     nullptr, nullptr, nullptr, bufB, st1, N_NODES);
        k_gemm<true><<<gemm_grid, 256, 0, stream>>>(bufB, Wb + (size_t)(3 + i) * 2048, b2 + i * D,
                                                    st1, g1 + i * D, bt1 + i * D, bufC, st2, N_NODES);
        k_readout<<<196, 256, 0, stream>>>((const unsigned int*)bufC, st2, g2 + i * D, bt2 + i * D,
                                           gp, bat, ro, i);
        H = bufC;
    }
    k_cls<<<NUM_GRAPHS, 128, 0, stream>>>(ro, Wc1, bc1, Wc2, bc2, out);
}